// Round 5
// baseline (340.648 us; speedup 1.0000x reference)
//
#include <hip/hip_runtime.h>
#include <hip/hip_bf16.h>

typedef __attribute__((ext_vector_type(8))) __bf16 bf16x8;
typedef __attribute__((ext_vector_type(4))) float f32x4;

#define BATCH 16
#define CH    64
#define NN    65536
#define BKE   128               // K floats per tile
#define KCHUNK 2048             // K per block
#define NT    (KCHUNK / BKE)    // 16 tiles
#define NC    (NN / KCHUNK)     // 32 chunks per batch
#define NB    256

__device__ __forceinline__ unsigned short f2bf(float f) {
  unsigned int u = __float_as_uint(f);
  u += 0x7FFFu + ((u >> 16) & 1u);   // RNE
  return (unsigned short)(u >> 16);
}

__global__ __launch_bounds__(256) void k_zero(float* p) {
  p[blockIdx.x * 256 + threadIdx.x] = 0.0f;
}

// Pass 1: energy[b,i,j] = sum_n x[b,i,n] x[b,j,n], split-K.
// v5 = v4 with ONE change: the global_load_lds LDS destination is built from
// a readfirstlane'd (SGPR-provable) wave base. v4 passed a threadIdx-derived
// LDS pointer -> compiler waterfall loop (~64x issue serialization), seen as
// VALUBusy 69% / MfmaUtil 1.4%. HW semantics (m104): LDS addr = uniform base
// + lane*size, so lane l's granule is base_g + l, matching its global src.
template <bool ATOMIC>
__global__ __launch_bounds__(256) void k_energy(const float* __restrict__ x,
                                                float* __restrict__ dst) {
  const int chunk = blockIdx.x;          // 0..NC-1
  const int b = blockIdx.y;              // 0..15
  const int t = threadIdx.x;
  const int w = t >> 6;                  // wave 0..3
  const int lane = t & 63;
  const int fr = lane & 15;
  const int grp = lane >> 4;

  __shared__ __align__(16) float s32[2][CH * BKE];        // 2 x 32 KiB, linear
  __shared__ __align__(16) unsigned short s16[CH * BKE];  // 16 KiB, swizzled

  f32x4 acc[4] = {};
  const float* xb = x + (size_t)b * CH * NN;
  const int k0 = chunk * KCHUNK;
  const int wu = __builtin_amdgcn_readfirstlane(w);  // SGPR wave id

  auto stage = [&](int buf, int tile) {
    const int kb = k0 + tile * BKE;
    char* ldsbase = ((char*)s32) + buf * (CH * BKE * 4);
    #pragma unroll
    for (int i = 0; i < 8; ++i) {        // 2048 granules of 16B / 256 threads
      const int gbase = i * 256 + wu * 64;   // wave-uniform granule base
      const int g = gbase + lane;            // this lane's granule
      const int row = g >> 5;                // 32 granules per 512B row
      const int cg = g & 31;
      const float* src = xb + (size_t)row * NN + kb + cg * 4;
      __builtin_amdgcn_global_load_lds(
          (const __attribute__((address_space(1))) void*)src,
          (__attribute__((address_space(3))) void*)(ldsbase + gbase * 16),
          16, 0, 0);                     // HW: dest = base + lane*16
    }
  };

  auto convert = [&](int buf) {
    #pragma unroll
    for (int i = 0; i < 8; ++i) {
      const int g = i * 256 + t;         // stride-1 granules: conflict-free
      const int row = g >> 5;
      const int cg = g & 31;
      const f32x4 v = *(const f32x4*)((const char*)&s32[buf][0] + (size_t)g * 16);
      ushort4 pk;
      pk.x = f2bf(v[0]); pk.y = f2bf(v[1]); pk.z = f2bf(v[2]); pk.w = f2bf(v[3]);
      int byte = row * 256 + cg * 8;     // bf16 row = 256B
      byte ^= (row & 7) << 4;            // XOR swizzle (G4)
      *(ushort4*)((char*)s16 + byte) = pk;
    }
  };

  auto mfma_tile = [&]() {
    const char* base = (const char*)s16;
    #pragma unroll
    for (int kk = 0; kk < BKE / 32; ++kk) {
      bf16x8 bfr[4];
      #pragma unroll
      for (int tt = 0; tt < 4; ++tt) {
        const int row = tt * 16 + fr;
        const int colb = kk * 64 + grp * 16;
        const int off = row * 256 + (colb ^ ((row & 7) << 4));
        bfr[tt] = *(const bf16x8*)(base + off);   // 2-way conflict = free
      }
      const bf16x8 af = bfr[w];                   // A rows == B rows for tt==w
      #pragma unroll
      for (int tt = 0; tt < 4; ++tt)
        acc[tt] = __builtin_amdgcn_mfma_f32_16x16x32_bf16(af, bfr[tt], acc[tt], 0, 0, 0);
    }
  };

  stage(0, 0);
  __syncthreads();                       // drain DMA(0)
  int cur = 0;
  for (int tile = 0; tile < NT; ++tile) {
    if (tile + 1 < NT) stage(cur ^ 1, tile + 1);  // async: flies through cvt+MFMA
    convert(cur);
    // bf16 tile ready: wait own ds_writes, barrier — do NOT drain vmcnt
    asm volatile("s_waitcnt lgkmcnt(0)" ::: "memory");
    __builtin_amdgcn_sched_barrier(0);
    __builtin_amdgcn_s_barrier();
    __builtin_amdgcn_sched_barrier(0);
    mfma_tile();
    __syncthreads();   // drains vmcnt(0): DMA(t+1) landed; all s16 reads done
    cur ^= 1;
  }

  // C/D layout (m89-verified): col = lane&15, row = (lane>>4)*4 + reg
  #pragma unroll
  for (int tt = 0; tt < 4; ++tt) {
    #pragma unroll
    for (int r = 0; r < 4; ++r) {
      const int i = w * 16 + grp * 4 + r;
      const int j = tt * 16 + fr;
      if (ATOMIC) {
        atomicAdd(&dst[((size_t)b * CH + i) * CH + j], acc[tt][r]);
      } else {
        float* p = dst + ((size_t)b * NC + chunk) * (CH * CH);
        p[i * CH + j] = acc[tt][r];
      }
    }
  }
}

// Fused reduce(+softmax): block (i,b), thread j sums NC partials (coalesced),
// wave-wide min/sum via shfl_xor. softmax(rowmax-e) = exp(minE-e)/sum.
// Writes TRANSPOSED attn_t[b][j][i].
__global__ __launch_bounds__(64) void k_redsm(const float* __restrict__ partial,
                                              float* __restrict__ attn_t) {
  const int i = blockIdx.x;
  const int b = blockIdx.y;
  const int j = threadIdx.x;
  const float* p = partial + (size_t)b * NC * (CH * CH) + i * CH + j;
  float e = 0.0f;
  #pragma unroll 8
  for (int c = 0; c < NC; ++c) e += p[(size_t)c * (CH * CH)];
  float mn = e;
  #pragma unroll
  for (int off = 32; off; off >>= 1) mn = fminf(mn, __shfl_xor(mn, off, 64));
  const float v = __expf(mn - e);
  float sum = v;
  #pragma unroll
  for (int off = 32; off; off >>= 1) sum += __shfl_xor(sum, off, 64);
  attn_t[(size_t)b * (CH * CH) + j * CH + i] = v / sum;
}

// Fallback softmax (atomic path): reads dense energy.
__global__ __launch_bounds__(64) void k_softmax(const float* __restrict__ energy,
                                                float* __restrict__ attn_t) {
  const int b = blockIdx.x;
  const int i = threadIdx.x;
  const float* e = energy + ((size_t)b * CH + i) * CH;
  float ev[CH];
  float mn = 3.402823466e38f;
  #pragma unroll
  for (int j = 0; j < CH; ++j) { ev[j] = e[j]; mn = fminf(mn, ev[j]); }
  float sum = 0.0f;
  #pragma unroll
  for (int j = 0; j < CH; ++j) { ev[j] = __expf(mn - ev[j]); sum += ev[j]; }
  const float inv = 1.0f / sum;
  #pragma unroll
  for (int j = 0; j < CH; ++j) attn_t[((size_t)b * CH + j) * CH + i] = ev[j] * inv;
}

// Pass 3: out[b,i,n] = gamma * sum_j attn[i,j] x[b,j,n] + x[b,i,n], fp32.
// ~6.7 TB/s vs 7.0 achievable — at floor, unchanged.
__global__ __launch_bounds__(256) void k_out(const float* __restrict__ x,
                                             const float* __restrict__ attn_t,
                                             const float* __restrict__ gamma,
                                             float* __restrict__ out) {
  const int b = blockIdx.y;
  const int n0 = blockIdx.x * NB;
  const int t = threadIdx.x;
  const int w = t >> 6;
  const int lane = t & 63;

  __shared__ __align__(16) float xsh[CH * NB];  // 64 KiB
  __shared__ __align__(16) float ash[CH * CH];  // 16 KiB

  const float* xb = x + (size_t)b * CH * NN;
  #pragma unroll
  for (int it = 0; it < 16; ++it) {
    const int flat = it * 256 + t;
    const int row = flat >> 6;
    const int c4 = flat & 63;
    *reinterpret_cast<f32x4*>(&xsh[row * NB + c4 * 4]) =
        *reinterpret_cast<const f32x4*>(xb + (size_t)row * NN + n0 + c4 * 4);
  }
  #pragma unroll
  for (int it = 0; it < 4; ++it) {
    const int flat = it * 256 + t;
    *reinterpret_cast<f32x4*>(&ash[flat * 4]) =
        *reinterpret_cast<const f32x4*>(attn_t + (size_t)b * CH * CH + flat * 4);
  }
  const float g = gamma[0];
  __syncthreads();

  f32x4 acc[16] = {};
  #pragma unroll 4
  for (int j = 0; j < CH; ++j) {
    const f32x4 xv = *reinterpret_cast<const f32x4*>(&xsh[j * NB + lane * 4]);
    #pragma unroll
    for (int q = 0; q < 4; ++q) {
      const f32x4 av = *reinterpret_cast<const f32x4*>(&ash[j * CH + w * 16 + q * 4]);
      acc[q * 4 + 0] += av[0] * xv;
      acc[q * 4 + 1] += av[1] * xv;
      acc[q * 4 + 2] += av[2] * xv;
      acc[q * 4 + 3] += av[3] * xv;
    }
  }
  float* ob = out + (size_t)b * CH * NN;
  #pragma unroll
  for (int r = 0; r < 16; ++r) {
    const int i = w * 16 + r;
    const f32x4 xv = *reinterpret_cast<const f32x4*>(&xsh[i * NB + lane * 4]);
    const f32x4 o = g * acc[r] + xv;  // exact fp32 epilogue
    *reinterpret_cast<f32x4*>(ob + (size_t)i * NN + n0 + lane * 4) = o;
  }
}

extern "C" void kernel_launch(void* const* d_in, const int* in_sizes, int n_in,
                              void* d_out, int out_size, void* d_ws, size_t ws_size,
                              hipStream_t stream) {
  const float* x = (const float*)d_in[0];
  const float* gamma = (const float*)d_in[1];
  float* out = (float*)d_out;

  const size_t part_elems = (size_t)BATCH * NC * CH * CH;   // 2M floats = 8.4 MB
  const size_t attn_elems = (size_t)BATCH * CH * CH;
  const size_t need = (part_elems + attn_elems) * sizeof(float);

  if (ws_size >= need) {
    float* partial = (float*)d_ws;
    float* attn_t = partial + part_elems;
    k_energy<false><<<dim3(NC, BATCH), 256, 0, stream>>>(x, partial);
    k_redsm<<<dim3(CH, BATCH), 64, 0, stream>>>(partial, attn_t);
    k_out<<<dim3(NN / NB, BATCH), 256, 0, stream>>>(x, attn_t, gamma, out);
  } else {
    float* energy = (float*)d_ws;
    float* attn_t = energy + attn_elems;
    k_zero<<<dim3((BATCH * CH * CH) / 256), 256, 0, stream>>>(energy);
    k_energy<true><<<dim3(NC, BATCH), 256, 0, stream>>>(x, energy);
    k_softmax<<<dim3(BATCH), 64, 0, stream>>>(energy, attn_t);
    k_out<<<dim3(NN / NB, BATCH), 256, 0, stream>>>(x, attn_t, gamma, out);
  }
}

// Round 6
// 200.711 us; speedup vs baseline: 1.6972x; 1.6972x over previous
//
#include <hip/hip_runtime.h>
#include <hip/hip_bf16.h>

typedef __attribute__((ext_vector_type(8))) __bf16 bf16x8;
typedef __attribute__((ext_vector_type(4))) float f32x4;

#define BATCH 16
#define CH    64
#define NN    65536
#define BKE   128               // K floats per LDS tile
#define KC    512               // K per block (partial path): 2048 blocks
#define NC    (NN / KC)         // 128 chunks per batch
#define KC_A  2048              // atomic fallback
#define NB    256

__device__ __forceinline__ unsigned short f2bf(float f) {
  unsigned int u = __float_as_uint(f);
  u += 0x7FFFu + ((u >> 16) & 1u);   // RNE
  return (unsigned short)(u >> 16);
}

__global__ __launch_bounds__(256) void k_zero(float* p) {
  p[blockIdx.x * 256 + threadIdx.x] = 0.0f;
}

// Pass 1: energy[b,i,j] = sum_n x[b,i,n] x[b,j,n], split-K.
// v6: back to reg-staging (R1/R2-proven codegen, VALUBusy ~4%) + T14
// issue-early. NO global_load_lds, NO runtime-indexed register arrays
// (rule #20 — v3..v5's `af = bfr[w]` was scratch-demoted).
// Per 64x128 tile: 8x global_load_dwordx4 -> f2bf once -> swizzled bf16
// ds_write (single 16 KiB buffer) -> MFMA; loads for tile t+1 issued
// before mfma(t) so HBM latency hides under MFMA + 5 blocks/CU TLP.
template <int KCHUNK, bool ATOMIC>
__global__ __launch_bounds__(256) void k_energy(const float* __restrict__ x,
                                                float* __restrict__ dst) {
  const int chunk = blockIdx.x;          // 0..NN/KCHUNK-1
  const int b = blockIdx.y;              // 0..15
  const int t = threadIdx.x;
  const int w = t >> 6;                  // wave 0..3
  const int lane = t & 63;
  const int fr = lane & 15;
  const int grp = lane >> 4;
  constexpr int NT = KCHUNK / BKE;

  __shared__ __align__(16) unsigned short s16[CH * BKE];  // 16 KiB, swizzled

  f32x4 acc[4] = {};
  f32x4 L[8];                            // staging regs (const-indexed only)
  const float* xb = x + (size_t)b * CH * NN;
  const int k0 = chunk * KCHUNK;

  auto load_tile = [&](int tile) {
    const int kb = k0 + tile * BKE;
    #pragma unroll
    for (int i = 0; i < 8; ++i) {        // granule g = i*256+t (coalesced 1KB/instr)
      const int g = i * 256 + t;
      const int row = g >> 5;            // 32 granules (16B) per 128-float row
      const int c4 = g & 31;
      L[i] = *(const f32x4*)(xb + (size_t)row * NN + kb + c4 * 4);
    }
  };

  auto write_lds = [&]() {
    #pragma unroll
    for (int i = 0; i < 8; ++i) {
      const int g = i * 256 + t;
      const int row = g >> 5;
      const int c4 = g & 31;
      ushort4 pk;
      pk.x = f2bf(L[i][0]); pk.y = f2bf(L[i][1]);
      pk.z = f2bf(L[i][2]); pk.w = f2bf(L[i][3]);
      const int byte = (row * 256 + c4 * 8) ^ ((row & 7) << 4);  // G4 swizzle
      *(ushort4*)((char*)s16 + byte) = pk;
    }
  };

  auto mfma_tile = [&]() {
    const char* base = (const char*)s16;
    #pragma unroll
    for (int kk = 0; kk < BKE / 32; ++kk) {
      const int colb = kk * 64 + grp * 16;
      const int arow = w * 16 + fr;
      const bf16x8 af =                      // A-frag: DIRECT load (no bfr[w])
          *(const bf16x8*)(base + (arow * 256 + (colb ^ ((arow & 7) << 4))));
      #pragma unroll
      for (int tt = 0; tt < 4; ++tt) {
        const int row = tt * 16 + fr;
        const bf16x8 bfr =
            *(const bf16x8*)(base + (row * 256 + (colb ^ ((row & 7) << 4))));
        acc[tt] = __builtin_amdgcn_mfma_f32_16x16x32_bf16(af, bfr, acc[tt], 0, 0, 0);
      }
    }
  };

  load_tile(0);
  for (int tile = 0; tile < NT; ++tile) {
    write_lds();                         // vmcnt waits inserted by compiler
    __syncthreads();                     // bf16 tile visible
    if (tile + 1 < NT) load_tile(tile + 1);  // issue-early: flies during MFMA
    mfma_tile();
    __syncthreads();                     // all frag reads done before overwrite
  }

  // C/D layout (m89-verified): col = lane&15, row = (lane>>4)*4 + reg
  #pragma unroll
  for (int tt = 0; tt < 4; ++tt) {
    #pragma unroll
    for (int r = 0; r < 4; ++r) {
      const int i = w * 16 + grp * 4 + r;
      const int j = tt * 16 + fr;
      if (ATOMIC) {
        atomicAdd(&dst[((size_t)b * CH + i) * CH + j], acc[tt][r]);
      } else {
        float* p = dst + ((size_t)b * (NN / KCHUNK) + chunk) * (CH * CH);
        p[i * CH + j] = acc[tt][r];
      }
    }
  }
}

// Fused reduce(+softmax): block (i,b), thread j sums NC partials (coalesced),
// wave-wide min/sum via shfl_xor. softmax(rowmax-e) = exp(minE-e)/sum.
// Writes TRANSPOSED attn_t[b][j][i].
__global__ __launch_bounds__(64) void k_redsm(const float* __restrict__ partial,
                                              float* __restrict__ attn_t) {
  const int i = blockIdx.x;
  const int b = blockIdx.y;
  const int j = threadIdx.x;
  const float* p = partial + (size_t)b * NC * (CH * CH) + i * CH + j;
  float e = 0.0f;
  #pragma unroll 8
  for (int c = 0; c < NC; ++c) e += p[(size_t)c * (CH * CH)];
  float mn = e;
  #pragma unroll
  for (int off = 32; off; off >>= 1) mn = fminf(mn, __shfl_xor(mn, off, 64));
  const float v = __expf(mn - e);
  float sum = v;
  #pragma unroll
  for (int off = 32; off; off >>= 1) sum += __shfl_xor(sum, off, 64);
  attn_t[(size_t)b * (CH * CH) + j * CH + i] = v / sum;
}

// Fallback softmax (atomic path): reads dense energy.
__global__ __launch_bounds__(64) void k_softmax(const float* __restrict__ energy,
                                                float* __restrict__ attn_t) {
  const int b = blockIdx.x;
  const int i = threadIdx.x;
  const float* e = energy + ((size_t)b * CH + i) * CH;
  float ev[CH];
  float mn = 3.402823466e38f;
  #pragma unroll
  for (int j = 0; j < CH; ++j) { ev[j] = e[j]; mn = fminf(mn, ev[j]); }
  float sum = 0.0f;
  #pragma unroll
  for (int j = 0; j < CH; ++j) { ev[j] = __expf(mn - ev[j]); sum += ev[j]; }
  const float inv = 1.0f / sum;
  #pragma unroll
  for (int j = 0; j < CH; ++j) attn_t[((size_t)b * CH + j) * CH + i] = ev[j] * inv;
}

// Pass 3: out[b,i,n] = gamma * sum_j attn[i,j] x[b,j,n] + x[b,i,n], fp32.
// ~6.6 TB/s vs ~7.0 achievable — at floor, unchanged.
__global__ __launch_bounds__(256) void k_out(const float* __restrict__ x,
                                             const float* __restrict__ attn_t,
                                             const float* __restrict__ gamma,
                                             float* __restrict__ out) {
  const int b = blockIdx.y;
  const int n0 = blockIdx.x * NB;
  const int t = threadIdx.x;
  const int w = t >> 6;
  const int lane = t & 63;

  __shared__ __align__(16) float xsh[CH * NB];  // 64 KiB
  __shared__ __align__(16) float ash[CH * CH];  // 16 KiB

  const float* xb = x + (size_t)b * CH * NN;
  #pragma unroll
  for (int it = 0; it < 16; ++it) {
    const int flat = it * 256 + t;
    const int row = flat >> 6;
    const int c4 = flat & 63;
    *reinterpret_cast<f32x4*>(&xsh[row * NB + c4 * 4]) =
        *reinterpret_cast<const f32x4*>(xb + (size_t)row * NN + n0 + c4 * 4);
  }
  #pragma unroll
  for (int it = 0; it < 4; ++it) {
    const int flat = it * 256 + t;
    *reinterpret_cast<f32x4*>(&ash[flat * 4]) =
        *reinterpret_cast<const f32x4*>(attn_t + (size_t)b * CH * CH + flat * 4);
  }
  const float g = gamma[0];
  __syncthreads();

  f32x4 acc[16] = {};
  #pragma unroll 4
  for (int j = 0; j < CH; ++j) {
    const f32x4 xv = *reinterpret_cast<const f32x4*>(&xsh[j * NB + lane * 4]);
    #pragma unroll
    for (int q = 0; q < 4; ++q) {
      const f32x4 av = *reinterpret_cast<const f32x4*>(&ash[j * CH + w * 16 + q * 4]);
      acc[q * 4 + 0] += av[0] * xv;
      acc[q * 4 + 1] += av[1] * xv;
      acc[q * 4 + 2] += av[2] * xv;
      acc[q * 4 + 3] += av[3] * xv;
    }
  }
  float* ob = out + (size_t)b * CH * NN;
  #pragma unroll
  for (int r = 0; r < 16; ++r) {
    const int i = w * 16 + r;
    const f32x4 xv = *reinterpret_cast<const f32x4*>(&xsh[i * NB + lane * 4]);
    const f32x4 o = g * acc[r] + xv;  // exact fp32 epilogue
    *reinterpret_cast<f32x4*>(ob + (size_t)i * NN + n0 + lane * 4) = o;
  }
}

extern "C" void kernel_launch(void* const* d_in, const int* in_sizes, int n_in,
                              void* d_out, int out_size, void* d_ws, size_t ws_size,
                              hipStream_t stream) {
  const float* x = (const float*)d_in[0];
  const float* gamma = (const float*)d_in[1];
  float* out = (float*)d_out;

  const size_t part_elems = (size_t)BATCH * NC * CH * CH;   // 8M floats = 32 MB
  const size_t attn_elems = (size_t)BATCH * CH * CH;
  const size_t need = (part_elems + attn_elems) * sizeof(float);

  if (ws_size >= need) {
    float* partial = (float*)d_ws;
    float* attn_t = partial + part_elems;
    k_energy<KC, false><<<dim3(NC, BATCH), 256, 0, stream>>>(x, partial);
    k_redsm<<<dim3(CH, BATCH), 64, 0, stream>>>(partial, attn_t);
    k_out<<<dim3(NN / NB, BATCH), 256, 0, stream>>>(x, attn_t, gamma, out);
  } else {
    float* energy = (float*)d_ws;
    float* attn_t = energy + attn_elems;
    k_zero<<<dim3((BATCH * CH * CH) / 256), 256, 0, stream>>>(energy);
    k_energy<KC_A, true><<<dim3(NN / KC_A, BATCH), 256, 0, stream>>>(x, energy);
    k_softmax<<<dim3(BATCH), 64, 0, stream>>>(energy, attn_t);
    k_out<<<dim3(NN / NB, BATCH), 256, 0, stream>>>(x, attn_t, gamma, out);
  }
}

// Round 7
// 195.905 us; speedup vs baseline: 1.7388x; 1.0245x over previous
//
#include <hip/hip_runtime.h>
#include <hip/hip_bf16.h>

typedef __attribute__((ext_vector_type(8))) __bf16 bf16x8;
typedef __attribute__((ext_vector_type(4))) float f32x4;

#define BATCH 16
#define CH    64
#define NN    65536
#define BKE   128               // K floats per LDS tile
#define KC    1024              // K per block: grid 64x16=1024 = 4 blocks/CU
#define NC    (NN / KC)         // 64 chunks per batch
#define KC_A  2048              // atomic fallback
#define NB    256

__device__ __forceinline__ unsigned short f2bf(float f) {
  unsigned int u = __float_as_uint(f);
  u += 0x7FFFu + ((u >> 16) & 1u);   // RNE
  return (unsigned short)(u >> 16);
}

__global__ __launch_bounds__(256) void k_zero(float* p) {
  p[blockIdx.x * 256 + threadIdx.x] = 0.0f;
}

// Pass 1: energy[b,i,j] = sum_n x[b,i,n] x[b,j,n], split-K.
// v7: true T3/T4 pipeline. v6's flaw: __syncthreads() drains vmcnt(0), so
// the "issue-early" loads were waited ~300cy after issue -> ~600cy exposed
// HBM latency per tile (measured 2.3 TB/s). Here:
//  - LDS double-buffer (2x16KB bf16), ONE raw barrier per tile, never a
//    vmcnt drain in steady state (barrier = lgkmcnt(0) + s_barrier only).
//  - 2-deep reg pipeline (named L0/L1, rule #20): tile t's loads are
//    consumed at tile t+2's write phase => ~2 tile periods (~1200cy) of
//    latency budget. Compiler emits counted vmcnt(8) by dependence (T4).
// Dbuf safety w/ one barrier: wave B's reads of buf X (tile t-1) complete
// before B's own MFMAs issue (lgkmcnt dep), hence before B arrives at
// barrier(t); wave A writes buf X (tile t+1) only after passing barrier(t).
template <int KCHUNK, bool ATOMIC>
__global__ __launch_bounds__(256, 4) void k_energy(const float* __restrict__ x,
                                                   float* __restrict__ dst) {
  constexpr int NT_ = KCHUNK / BKE;      // 8 (partial) / 16 (fallback)
  const int chunk = blockIdx.x;
  const int b = blockIdx.y;
  const int t = threadIdx.x;
  const int w = t >> 6;
  const int lane = t & 63;
  const int fr = lane & 15;
  const int grp = lane >> 4;
  const int w16 = w * 16;

  __shared__ __align__(16) unsigned short s16[2][CH * BKE];  // 2 x 16 KiB

  f32x4 acc[4] = {};
  f32x4 L0[8], L1[8];                    // two reg staging sets, const-indexed
  const float* xb = x + (size_t)b * CH * NN;
  const int k0 = chunk * KCHUNK;

#define LOADT(Lx, tile) do {                                                  \
    const int kb = k0 + (tile) * BKE;                                         \
    _Pragma("unroll")                                                         \
    for (int i = 0; i < 8; ++i) {                                             \
      const int g = i * 256 + t;                                              \
      const int row = g >> 5;            /* 32x16B granules per 128f row */   \
      const int c4 = g & 31;                                                  \
      Lx[i] = *(const f32x4*)(xb + (size_t)row * NN + kb + c4 * 4);           \
    }                                                                         \
  } while (0)

#define STEP(Lx, tile) do {                                                   \
    unsigned short* sb = s16[(tile) & 1];                                     \
    _Pragma("unroll")                                                         \
    for (int i = 0; i < 8; ++i) {        /* waits: counted vmcnt (dep) */     \
      const int g = i * 256 + t;                                              \
      const int row = g >> 5;                                                 \
      const int c4 = g & 31;                                                  \
      ushort4 pk;                                                             \
      pk.x = f2bf(Lx[i][0]); pk.y = f2bf(Lx[i][1]);                           \
      pk.z = f2bf(Lx[i][2]); pk.w = f2bf(Lx[i][3]);                           \
      const int byte = (row * 256 + c4 * 8) ^ ((row & 7) << 4);               \
      *(ushort4*)((char*)sb + byte) = pk;                                     \
    }                                                                         \
    if ((tile) + 2 < NT_) LOADT(Lx, (tile) + 2);   /* refill, 2-deep */       \
    __builtin_amdgcn_sched_barrier(0);                                        \
    asm volatile("s_waitcnt lgkmcnt(0)" ::: "memory");                        \
    __builtin_amdgcn_sched_barrier(0);                                        \
    __builtin_amdgcn_s_barrier();        /* raw: vmcnt stays in flight */     \
    __builtin_amdgcn_sched_barrier(0);                                        \
    const char* base = (const char*)sb;                                       \
    _Pragma("unroll")                                                         \
    for (int kk = 0; kk < BKE / 32; ++kk) {                                   \
      const int colb = kk * 64 + grp * 16;                                    \
      const int arow = w16 + fr;                                              \
      const bf16x8 af =                                                       \
          *(const bf16x8*)(base + (arow * 256 + (colb ^ ((arow & 7) << 4)))); \
      _Pragma("unroll")                                                       \
      for (int tt = 0; tt < 4; ++tt) {                                        \
        const int rw = tt * 16 + fr;                                          \
        const bf16x8 bfr =                                                    \
            *(const bf16x8*)(base + (rw * 256 + (colb ^ ((rw & 7) << 4))));   \
        acc[tt] = __builtin_amdgcn_mfma_f32_16x16x32_bf16(af, bfr, acc[tt],   \
                                                          0, 0, 0);           \
      }                                                                       \
    }                                                                         \
  } while (0)

  LOADT(L0, 0);
  LOADT(L1, 1);
  #pragma unroll
  for (int tile = 0; tile < NT_; tile += 2) {
    STEP(L0, tile);
    STEP(L1, tile + 1);
  }
#undef STEP
#undef LOADT

  // C/D layout (m89-verified): col = lane&15, row = (lane>>4)*4 + reg
  #pragma unroll
  for (int tt = 0; tt < 4; ++tt) {
    #pragma unroll
    for (int r = 0; r < 4; ++r) {
      const int i = w16 + grp * 4 + r;
      const int j = tt * 16 + fr;
      if (ATOMIC) {
        atomicAdd(&dst[((size_t)b * CH + i) * CH + j], acc[tt][r]);
      } else {
        float* p = dst + ((size_t)b * (NN / KCHUNK) + chunk) * (CH * CH);
        p[i * CH + j] = acc[tt][r];
      }
    }
  }
}

// Fused reduce(+softmax): block (i,b), thread j sums NC partials (coalesced),
// wave-wide min/sum via shfl_xor. softmax(rowmax-e) = exp(minE-e)/sum.
// Writes TRANSPOSED attn_t[b][j][i].
__global__ __launch_bounds__(64) void k_redsm(const float* __restrict__ partial,
                                              float* __restrict__ attn_t) {
  const int i = blockIdx.x;
  const int b = blockIdx.y;
  const int j = threadIdx.x;
  const float* p = partial + (size_t)b * NC * (CH * CH) + i * CH + j;
  float e = 0.0f;
  #pragma unroll 8
  for (int c = 0; c < NC; ++c) e += p[(size_t)c * (CH * CH)];
  float mn = e;
  #pragma unroll
  for (int off = 32; off; off >>= 1) mn = fminf(mn, __shfl_xor(mn, off, 64));
  const float v = __expf(mn - e);
  float sum = v;
  #pragma unroll
  for (int off = 32; off; off >>= 1) sum += __shfl_xor(sum, off, 64);
  attn_t[(size_t)b * (CH * CH) + j * CH + i] = v / sum;
}

// Fallback softmax (atomic path): reads dense energy.
__global__ __launch_bounds__(64) void k_softmax(const float* __restrict__ energy,
                                                float* __restrict__ attn_t) {
  const int b = blockIdx.x;
  const int i = threadIdx.x;
  const float* e = energy + ((size_t)b * CH + i) * CH;
  float ev[CH];
  float mn = 3.402823466e38f;
  #pragma unroll
  for (int j = 0; j < CH; ++j) { ev[j] = e[j]; mn = fminf(mn, ev[j]); }
  float sum = 0.0f;
  #pragma unroll
  for (int j = 0; j < CH; ++j) { ev[j] = __expf(mn - ev[j]); sum += ev[j]; }
  const float inv = 1.0f / sum;
  #pragma unroll
  for (int j = 0; j < CH; ++j) attn_t[((size_t)b * CH + j) * CH + i] = ev[j] * inv;
}

// Pass 3: out[b,i,n] = gamma * sum_j attn[i,j] x[b,j,n] + x[b,i,n], fp32.
// ~6.6 TB/s vs ~7.0 achievable — at floor, unchanged.
__global__ __launch_bounds__(256) void k_out(const float* __restrict__ x,
                                             const float* __restrict__ attn_t,
                                             const float* __restrict__ gamma,
                                             float* __restrict__ out) {
  const int b = blockIdx.y;
  const int n0 = blockIdx.x * NB;
  const int t = threadIdx.x;
  const int w = t >> 6;
  const int lane = t & 63;

  __shared__ __align__(16) float xsh[CH * NB];  // 64 KiB
  __shared__ __align__(16) float ash[CH * CH];  // 16 KiB

  const float* xb = x + (size_t)b * CH * NN;
  #pragma unroll
  for (int it = 0; it < 16; ++it) {
    const int flat = it * 256 + t;
    const int row = flat >> 6;
    const int c4 = flat & 63;
    *reinterpret_cast<f32x4*>(&xsh[row * NB + c4 * 4]) =
        *reinterpret_cast<const f32x4*>(xb + (size_t)row * NN + n0 + c4 * 4);
  }
  #pragma unroll
  for (int it = 0; it < 4; ++it) {
    const int flat = it * 256 + t;
    *reinterpret_cast<f32x4*>(&ash[flat * 4]) =
        *reinterpret_cast<const f32x4*>(attn_t + (size_t)b * CH * CH + flat * 4);
  }
  const float g = gamma[0];
  __syncthreads();

  f32x4 acc[16] = {};
  #pragma unroll 4
  for (int j = 0; j < CH; ++j) {
    const f32x4 xv = *reinterpret_cast<const f32x4*>(&xsh[j * NB + lane * 4]);
    #pragma unroll
    for (int q = 0; q < 4; ++q) {
      const f32x4 av = *reinterpret_cast<const f32x4*>(&ash[j * CH + w * 16 + q * 4]);
      acc[q * 4 + 0] += av[0] * xv;
      acc[q * 4 + 1] += av[1] * xv;
      acc[q * 4 + 2] += av[2] * xv;
      acc[q * 4 + 3] += av[3] * xv;
    }
  }
  float* ob = out + (size_t)b * CH * NN;
  #pragma unroll
  for (int r = 0; r < 16; ++r) {
    const int i = w * 16 + r;
    const f32x4 xv = *reinterpret_cast<const f32x4*>(&xsh[i * NB + lane * 4]);
    const f32x4 o = g * acc[r] + xv;  // exact fp32 epilogue
    *reinterpret_cast<f32x4*>(ob + (size_t)i * NN + n0 + lane * 4) = o;
  }
}

extern "C" void kernel_launch(void* const* d_in, const int* in_sizes, int n_in,
                              void* d_out, int out_size, void* d_ws, size_t ws_size,
                              hipStream_t stream) {
  const float* x = (const float*)d_in[0];
  const float* gamma = (const float*)d_in[1];
  float* out = (float*)d_out;

  const size_t part_elems = (size_t)BATCH * NC * CH * CH;   // 4M floats = 16.8 MB
  const size_t attn_elems = (size_t)BATCH * CH * CH;
  const size_t need = (part_elems + attn_elems) * sizeof(float);

  if (ws_size >= need) {
    float* partial = (float*)d_ws;
    float* attn_t = partial + part_elems;
    k_energy<KC, false><<<dim3(NC, BATCH), 256, 0, stream>>>(x, partial);
    k_redsm<<<dim3(CH, BATCH), 64, 0, stream>>>(partial, attn_t);
    k_out<<<dim3(NN / NB, BATCH), 256, 0, stream>>>(x, attn_t, gamma, out);
  } else {
    float* energy = (float*)d_ws;
    float* attn_t = energy + attn_elems;
    k_zero<<<dim3((BATCH * CH * CH) / 256), 256, 0, stream>>>(energy);
    k_energy<KC_A, true><<<dim3(NN / KC_A, BATCH), 256, 0, stream>>>(x, energy);
    k_softmax<<<dim3(BATCH), 64, 0, stream>>>(energy, attn_t);
    k_out<<<dim3(NN / NB, BATCH), 256, 0, stream>>>(x, attn_t, gamma, out);
  }
}